// Round 1
// baseline (420.191 us; speedup 1.0000x reference)
//
#include <hip/hip_runtime.h>

// Problem constants (from reference): B=8192, K=512, C=16
#define B_SZ 8192
#define K_SZ 512
#define C_SZ 16

// One thread per (b,c) pair. mask is [B, C, K] with guaranteed contiguous
// leading-ones rows, so run length = index of first zero, found by binary
// search (9 probes instead of 512 coalesced reads: ~75 MB of cachelines vs
// 256 MB full read).
__global__ __launch_bounds__(256) void rocloss_kernel(
    const float* __restrict__ logits,   // [B, K, C] f32
    const int*   __restrict__ target,   // [B] i32
    const int*   __restrict__ mask,     // [B, C, K] i32 (leading-ones rows)
    float*       __restrict__ out)      // [1] f32 (pre-zeroed)
{
    const int gid = blockIdx.x * 256 + threadIdx.x;   // 0 .. B*C-1
    const int b = gid >> 4;      // / C_SZ
    const int c = gid & 15;      // % C_SZ

    // Binary search the first zero index p in [1, K]. Row has >=1 leading one.
    // Search space size 512 -> exactly 9 iterations, uniform across lanes.
    const int* __restrict__ row = mask + (size_t)gid * K_SZ;  // gid == b*C + c
    int lo = 1, hi = K_SZ;
    #pragma unroll 1
    while (lo < hi) {
        int mid = (lo + hi) >> 1;          // in [1, 511]
        if (row[mid]) lo = mid + 1; else hi = mid;
    }
    const int t = lo - 1;                  // counter = run_length - 1

    // Gather the logit at the last valid timestep: logits[b][t][c]
    const float a = logits[((size_t)b * K_SZ + (size_t)t) * C_SZ + c];

    // log-softmax over the 16 candidates (c dim) via width-16 shuffles.
    float m = a;
    #pragma unroll
    for (int off = 8; off; off >>= 1)
        m = fmaxf(m, __shfl_xor(m, off, 16));
    const float e = __expf(a - m);
    float s = e;
    #pragma unroll
    for (int off = 8; off; off >>= 1)
        s += __shfl_xor(s, off, 16);
    const float lse = m + __logf(s);       // logsumexp of the 16 adjusted logits

    // loss_b = lse - a[target[b]]; mean over B. One atomic per block.
    __shared__ float acc;
    if (threadIdx.x == 0) acc = 0.0f;
    __syncthreads();
    const int tgt = target[b];
    if (c == tgt) {
        atomicAdd(&acc, lse - a);
    }
    __syncthreads();
    if (threadIdx.x == 0) {
        atomicAdd(out, acc * (1.0f / (float)B_SZ));
    }
}

extern "C" void kernel_launch(void* const* d_in, const int* in_sizes, int n_in,
                              void* d_out, int out_size, void* d_ws, size_t ws_size,
                              hipStream_t stream) {
    const float* logits = (const float*)d_in[0];   // [B,K,C] f32
    const int*   target = (const int*)d_in[1];     // [B] i32
    const int*   mask   = (const int*)d_in[2];     // [B,C,K] i32
    float* out = (float*)d_out;

    // d_out is poisoned with 0xAA before every launch; zero it for the atomics.
    hipMemsetAsync(out, 0, sizeof(float), stream);

    const int total = B_SZ * C_SZ;                 // 131072 threads
    rocloss_kernel<<<total / 256, 256, 0, stream>>>(logits, target, mask, out);
}

// Round 2
// 417.940 us; speedup vs baseline: 1.0054x; 1.0054x over previous
//
#include <hip/hip_runtime.h>

// Problem constants (from reference): B=8192, K=512, C=16
#define B_SZ 8192
#define K_SZ 512
#define C_SZ 16

// One thread per (b,c) pair. mask is [B, C, K] i32 with guaranteed contiguous
// leading-ones rows (run length p in [1,512]); all entries after the run are 0.
//
// R2: cacheline-granular search. Instead of a 9-probe element binary search
// (9 scattered 64B-line fetches per row), binary-search the 32 cachelines of
// the row for the last line whose first element is 1 (5 probes), then read
// that one line and sum it: t = 16*lmax + sum(line) - 1.
// Distinct lines/row: ~6 vs 9 -> ~50 MB mask fetch vs 75 MB, and a 6-deep
// (vs 9-deep) dependent-miss chain.
__global__ __launch_bounds__(256) void rocloss_kernel(
    const float* __restrict__ logits,   // [B, K, C] f32
    const int*   __restrict__ target,   // [B] i32
    const int*   __restrict__ mask,     // [B, C, K] i32 (leading-ones rows)
    float*       __restrict__ out)      // [1] f32 (pre-zeroed)
{
    const int gid = blockIdx.x * 256 + threadIdx.x;   // 0 .. B*C-1
    const int b = gid >> 4;      // / C_SZ
    const int c = gid & 15;      // % C_SZ

    const int* __restrict__ row = mask + (size_t)gid * K_SZ;  // gid == b*C + c

    // Find lmax = max { l in [0,32) : row[16*l] == 1 }.  row[0] == 1 is
    // guaranteed (p >= 1).  Exactly 5 iterations (span 32->16->8->4->2->1),
    // uniform across lanes.
    int lo = 0, hi = 31;
    #pragma unroll 1
    while (lo < hi) {
        int mid = (lo + hi + 1) >> 1;     // in [1,31]
        if (row[mid << 4]) lo = mid; else hi = mid - 1;
    }

    // Boundary is inside line lo: p = 16*lo + s, s = popcount of that line.
    // One 64B line read (4x int4, single L1 line), branch-free sum.
    const int4* __restrict__ line = (const int4*)(row + (lo << 4));
    int4 q0 = line[0];
    int4 q1 = line[1];
    int4 q2 = line[2];
    int4 q3 = line[3];
    int s = (q0.x + q0.y + q0.z + q0.w)
          + (q1.x + q1.y + q1.z + q1.w)
          + (q2.x + q2.y + q2.z + q2.w)
          + (q3.x + q3.y + q3.z + q3.w);
    const int t = (lo << 4) + s - 1;       // counter = run_length - 1

    // Gather the logit at the last valid timestep: logits[b][t][c]
    const float a = logits[((size_t)b * K_SZ + (size_t)t) * C_SZ + c];

    // log-softmax over the 16 candidates (c dim) via width-16 shuffles.
    float m = a;
    #pragma unroll
    for (int off = 8; off; off >>= 1)
        m = fmaxf(m, __shfl_xor(m, off, 16));
    const float e = __expf(a - m);
    float s2 = e;
    #pragma unroll
    for (int off = 8; off; off >>= 1)
        s2 += __shfl_xor(s2, off, 16);
    const float lse = m + __logf(s2);      // logsumexp of the 16 adjusted logits

    // loss_b = lse - a[target[b]]; mean over B. One atomic per block.
    __shared__ float acc;
    if (threadIdx.x == 0) acc = 0.0f;
    __syncthreads();
    const int tgt = target[b];
    if (c == tgt) {
        atomicAdd(&acc, lse - a);
    }
    __syncthreads();
    if (threadIdx.x == 0) {
        atomicAdd(out, acc * (1.0f / (float)B_SZ));
    }
}

extern "C" void kernel_launch(void* const* d_in, const int* in_sizes, int n_in,
                              void* d_out, int out_size, void* d_ws, size_t ws_size,
                              hipStream_t stream) {
    const float* logits = (const float*)d_in[0];   // [B,K,C] f32
    const int*   target = (const int*)d_in[1];     // [B] i32
    const int*   mask   = (const int*)d_in[2];     // [B,C,K] i32
    float* out = (float*)d_out;

    // d_out is poisoned with 0xAA before every launch; zero it for the atomics.
    hipMemsetAsync(out, 0, sizeof(float), stream);

    const int total = B_SZ * C_SZ;                 // 131072 threads
    rocloss_kernel<<<total / 256, 256, 0, stream>>>(logits, target, mask, out);
}